// Round 2
// baseline (306.174 us; speedup 1.0000x reference)
//
#include <hip/hip_runtime.h>

// Conv bank of 17 fixed filters + ReLU over (128,1,32768) fp32.
// out[b,j,t] = relu( sum_k W[j,k] * x[b, t + k - 47] ), W is the (17,96)
// center-aligned bank from the reference (pad 47 left / 48 right).
//
// Filters 6..11 are exact negations of 0..5 -> compute 11 unique filters,
// emit 17 rows.  Direct streaming accumulation:
//   - one plain LDS tile xs[1120], ONE barrier
//   - each thread owns 4 consecutive outputs; reads its 100-float window as
//     25 ds_read_b128 (lane-contiguous 16B -> conflict-free, imm offsets)
//   - weights come from a constexpr bank -> folded to immediates; alt
//     weights are +-1 (inline constants), bump weights are ~32 distinct
//     literals the compiler hoists once
// Write-bandwidth-bound target: 285 MB stores ~ 45 us @ 6.3 TB/s.

#define S_LEN    32768
#define NFILT    17
#define TILE     1024
#define HALO_L   47
#define WIN      (TILE + 96)   // 1120 staged floats per block
#define NTHREADS 256
#define NCHUNKS  25            // d = 0..99 covers k in [0,96) for r in [0,4)

struct BankT {
    float w[11][96];
    constexpr BankT() : w{} {
        const int KS[6] = {2, 4, 8, 16, 32, 64};
        // f = 0..5 : alternating filters, even indices = -1 (even_negative)
        for (int fi = 0; fi < 6; ++fi) {
            const int K = KS[fi];
            const int o = 47 - (K - 1) / 2;
            for (int i = 0; i < K; ++i)
                w[fi][o + i] = (i % 2 == 0) ? -1.0f : 1.0f;
        }
        // f = 6..10 : quadratic bumps [-L,-R,2L,2R,-L,-R], K = 4..64
        for (int fi = 0; fi < 5; ++fi) {
            const int K = KS[fi + 1];
            const int Q = K / 4;
            const int o = 47 - (3 * K / 2 - 1) / 2;
            for (int j = 0; j < 6 * Q; ++j) {
                const int seg = j / Q, i = j - seg * Q;
                const float t = (seg == 0 || seg == 2 || seg == 4)
                                ? (float)(i + 1) / (float)Q
                                : (float)(Q - i) / (float)Q;
                const float v = t * t;
                w[fi + 6][o + j] = (seg == 2 || seg == 3) ? 2.0f * v : -v;
            }
        }
    }
};
__constant__ constexpr BankT BANK;   // only ever read with constant indices -> folded

__global__ __launch_bounds__(NTHREADS)
void conv_bank_kernel(const float* __restrict__ x, float* __restrict__ out) {
    __shared__ float xs[WIN];

    const int tid = threadIdx.x;
    const int ts  = blockIdx.x * TILE;
    const int b   = blockIdx.y;
    const float* __restrict__ xrow = x + (size_t)b * S_LEN;

    // ---- stage tile + halo (zero-padded at row edges), plain layout ----
#pragma unroll
    for (int j0 = 0; j0 < WIN; j0 += NTHREADS) {
        const int j = j0 + tid;
        if (j0 + NTHREADS <= WIN || j < WIN) {
            const int g = ts - HALO_L + j;
            xs[j] = ((unsigned)g < (unsigned)S_LEN) ? xrow[g] : 0.0f;
        }
    }
    __syncthreads();

    // ---- stream 25 x float4 LDS reads, accumulate 11 filters x 4 positions ----
    float acc[11][4];
#pragma unroll
    for (int f = 0; f < 11; ++f)
#pragma unroll
        for (int r = 0; r < 4; ++r) acc[f][r] = 0.0f;

    const float4* __restrict__ xv4 = reinterpret_cast<const float4*>(xs) + tid;
#pragma unroll
    for (int c = 0; c < NCHUNKS; ++c) {
        const float4 xq = xv4[c];
        const float xe[4] = {xq.x, xq.y, xq.z, xq.w};
#pragma unroll
        for (int l = 0; l < 4; ++l) {
            const int d = 4 * c + l;     // xs logical offset rel. to 4*tid
#pragma unroll
            for (int r = 0; r < 4; ++r) {
                const int k = d - r;     // bank column
                if (k >= 0 && k < 96) {
#pragma unroll
                    for (int f = 0; f < 11; ++f) {
                        const float wv = BANK.w[f][k];   // compile-time const
                        if (wv != 0.0f)
                            acc[f][r] = fmaf(wv, xe[l], acc[f][r]);
                    }
                }
            }
        }
    }

    // ---- relu + float4 stores, 17 rows (6 negated pairs come free) ----
    const int t0 = ts + 4 * tid;
    float* __restrict__ obase = out + (size_t)b * NFILT * S_LEN + t0;

    auto store_relu = [&](int row, float a0, float a1, float a2, float a3) {
        const float4 s = make_float4(fmaxf(a0, 0.f), fmaxf(a1, 0.f),
                                     fmaxf(a2, 0.f), fmaxf(a3, 0.f));
        *reinterpret_cast<float4*>(obase + (size_t)row * S_LEN) = s;
    };

#pragma unroll
    for (int f = 0; f < 6; ++f) {
        store_relu(f,      acc[f][0],  acc[f][1],  acc[f][2],  acc[f][3]);
        store_relu(f + 6, -acc[f][0], -acc[f][1], -acc[f][2], -acc[f][3]);
    }
#pragma unroll
    for (int f = 0; f < 5; ++f)
        store_relu(12 + f, acc[6 + f][0], acc[6 + f][1],
                           acc[6 + f][2], acc[6 + f][3]);
}

extern "C" void kernel_launch(void* const* d_in, const int* in_sizes, int n_in,
                              void* d_out, int out_size, void* d_ws, size_t ws_size,
                              hipStream_t stream) {
    const float* x = (const float*)d_in[0];
    float* out = (float*)d_out;
    const int nbatch = in_sizes[0] / S_LEN;   // 128
    dim3 grid(S_LEN / TILE, nbatch, 1);
    conv_bank_kernel<<<grid, NTHREADS, 0, stream>>>(x, out);
}